// Round 2
// baseline (660.993 us; speedup 1.0000x reference)
//
#include <hip/hip_runtime.h>

#define TOKENS 4096
#define HIDDEN 4096
#define FFN    14336
#define R      16
#define SCALING 2.0f

// ---------------------------------------------------------------------------
// ws layout (floats):
//   w2aT : FFN*16          transposed w2_A for contiguous row reads
//   h13  : 2*TOKENS*32     split-K partial x-projections (no bias)
//   h2   : TOKENS*16       accumulated h@w2_A.T (atomics, zeroed per call)
// ---------------------------------------------------------------------------

__global__ __launch_bounds__(256) void k_transpose_w2a(
    const float* __restrict__ w2A, float* __restrict__ w2aT)
{
    int idx = blockIdx.x * 256 + threadIdx.x;   // over R*FFN, f-fastest: coalesced read
    if (idx < R * FFN) {
        int r = idx / FFN, f = idx % FFN;
        w2aT[(size_t)f * R + r] = w2A[idx];
    }
}

// K1: split-K x-projection. No LDS, no barriers. x reads are half-wave-uniform
// (L1 broadcast); weight rows L2-resident. Grid (TOKENS/8, 2), 16 waves/CU.
#define K1_SPLIT 2
#define K1_HC (HIDDEN / K1_SPLIT)

__global__ __launch_bounds__(256) void k1_xproj(
    const float* __restrict__ x,
    const float* __restrict__ w1A, const float* __restrict__ w3A,
    float* __restrict__ h13)   // [K1_SPLIT][TOKENS][32]
{
    const int tid  = threadIdx.x;
    const int tloc = tid >> 5;     // 0..7 token within tile
    const int rr   = tid & 31;     // 0..31 output (16 for w1, 16 for w3)
    const int t    = blockIdx.x * 8 + tloc;
    const int h0   = blockIdx.y * K1_HC;

    const float* xp = x + (size_t)t * HIDDEN + h0;
    const float* wp = ((rr < 16) ? (w1A + (size_t)rr * HIDDEN)
                                 : (w3A + (size_t)(rr - 16) * HIDDEN)) + h0;
    float acc = 0.f;
    #pragma unroll 4
    for (int hh = 0; hh < K1_HC; hh += 4) {
        float4 xv = *reinterpret_cast<const float4*>(xp + hh);
        float4 wv = *reinterpret_cast<const float4*>(wp + hh);
        acc = fmaf(xv.x, wv.x, acc);
        acc = fmaf(xv.y, wv.y, acc);
        acc = fmaf(xv.z, wv.z, acc);
        acc = fmaf(xv.w, wv.w, acc);
    }
    h13[((size_t)blockIdx.y * TOKENS + t) * 32 + rr] = acc;
}

// K2: fused middle. Block = 64 tokens x 4 f-segments (one wave per f-segment,
// so weight-row addresses are wave-uniform -> scalar/L1-broadcast loads, zero
// LDS in the hot loop). Grid (64, 28) = 1792 blocks. Cross-wave reduce in LDS,
// then one atomicAdd per (token,r) per block.
#define K2_TOK   64
#define K2_FPT   128
#define K2_WAVES 4

__global__ __launch_bounds__(256) void k2_mid(
    const float* __restrict__ h13,      // [2][TOKENS][32]
    const float* __restrict__ w1Ab, const float* __restrict__ w3Ab,
    const float* __restrict__ w1B,  const float* __restrict__ w1Bb,
    const float* __restrict__ w3B,  const float* __restrict__ w3Bb,
    const float* __restrict__ w2aT,
    float* __restrict__ h2)
{
    __shared__ float red[K2_WAVES][K2_TOK][17];   // padded: conflict-free
    const int tid   = threadIdx.x;
    const int tloc  = tid & 63;
    const int fseg  = tid >> 6;
    const int t     = blockIdx.x * K2_TOK + tloc;
    const int fbase = blockIdx.y * (K2_FPT * K2_WAVES) + fseg * K2_FPT;

    const float* ha0 = h13 + (size_t)t * 32;
    const float* ha1 = h13 + (size_t)TOKENS * 32 + (size_t)t * 32;

    float hA[16], hB[16], acc[16];
    #pragma unroll
    for (int k = 0; k < 4; ++k) {
        float4 a = *reinterpret_cast<const float4*>(ha0 + k * 4);
        float4 b = *reinterpret_cast<const float4*>(ha1 + k * 4);
        float4 bs = *reinterpret_cast<const float4*>(w1Ab + k * 4);
        hA[4*k+0] = a.x + b.x + bs.x;
        hA[4*k+1] = a.y + b.y + bs.y;
        hA[4*k+2] = a.z + b.z + bs.z;
        hA[4*k+3] = a.w + b.w + bs.w;
    }
    #pragma unroll
    for (int k = 0; k < 4; ++k) {
        float4 a = *reinterpret_cast<const float4*>(ha0 + 16 + k * 4);
        float4 b = *reinterpret_cast<const float4*>(ha1 + 16 + k * 4);
        float4 bs = *reinterpret_cast<const float4*>(w3Ab + k * 4);
        hB[4*k+0] = a.x + b.x + bs.x;
        hB[4*k+1] = a.y + b.y + bs.y;
        hB[4*k+2] = a.z + b.z + bs.z;
        hB[4*k+3] = a.w + b.w + bs.w;
    }
    #pragma unroll
    for (int r = 0; r < 16; ++r) acc[r] = 0.f;

    #pragma unroll 2
    for (int fl = 0; fl < K2_FPT; ++fl) {
        const size_t f = (size_t)(fbase + fl);
        const float4* wb1 = reinterpret_cast<const float4*>(w1B  + f * 16);
        const float4* wb3 = reinterpret_cast<const float4*>(w3B  + f * 16);
        const float4* wa2 = reinterpret_cast<const float4*>(w2aT + f * 16);
        float g  = w1Bb[f];
        float uu = w3Bb[f];
        #pragma unroll
        for (int k = 0; k < 4; ++k) {
            float4 a = wb1[k];
            g = fmaf(hA[4*k+0], a.x, g);
            g = fmaf(hA[4*k+1], a.y, g);
            g = fmaf(hA[4*k+2], a.z, g);
            g = fmaf(hA[4*k+3], a.w, g);
        }
        #pragma unroll
        for (int k = 0; k < 4; ++k) {
            float4 a = wb3[k];
            uu = fmaf(hB[4*k+0], a.x, uu);
            uu = fmaf(hB[4*k+1], a.y, uu);
            uu = fmaf(hB[4*k+2], a.z, uu);
            uu = fmaf(hB[4*k+3], a.w, uu);
        }
        g  *= SCALING;
        uu *= SCALING;
        float sig = __builtin_amdgcn_rcpf(1.f + __expf(-g));
        float hv  = g * sig * uu;
        #pragma unroll
        for (int k = 0; k < 4; ++k) {
            float4 a = wa2[k];
            acc[4*k+0] = fmaf(hv, a.x, acc[4*k+0]);
            acc[4*k+1] = fmaf(hv, a.y, acc[4*k+1]);
            acc[4*k+2] = fmaf(hv, a.z, acc[4*k+2]);
            acc[4*k+3] = fmaf(hv, a.w, acc[4*k+3]);
        }
    }

    // cross-wave reduce, then 1 atomic per (t,r)
    #pragma unroll
    for (int r = 0; r < 16; ++r) red[fseg][tloc][r] = acc[r];
    __syncthreads();
    for (int i = tid; i < K2_TOK * 16; i += 256) {
        int tt = i >> 4, r = i & 15;
        float s = red[0][tt][r] + red[1][tt][r] + red[2][tt][r] + red[3][tt][r];
        atomicAdd(&h2[(size_t)(blockIdx.x * K2_TOK + tt) * 16 + r], s);
    }
}

// K3: out[t][o] = (sum_r (h2[t][r]+w2Ab[r]) * w2B[o][r] + w2Bb[o]) * 2
__global__ __launch_bounds__(256) void k3_out(
    const float* __restrict__ h2,
    const float* __restrict__ w2Ab,
    const float* __restrict__ w2B, const float* __restrict__ w2Bb,
    float* __restrict__ out)
{
    __shared__ float s_h2[16][16];
    const int tid = threadIdx.x;
    const int t0  = blockIdx.x * 16;
    const int o0  = blockIdx.y * 1024;

    {
        int t = tid >> 4, r = tid & 15;
        s_h2[t][r] = h2[(size_t)(t0 + t) * 16 + r] + w2Ab[r];
    }
    __syncthreads();

    const int ob = o0 + tid * 4;
    float w[4][16];
    #pragma unroll
    for (int j = 0; j < 4; ++j) {
        #pragma unroll
        for (int k = 0; k < 4; ++k) {
            float4 v = *reinterpret_cast<const float4*>(
                w2B + (size_t)(ob + j) * 16 + k * 4);
            w[j][4*k+0] = v.x; w[j][4*k+1] = v.y;
            w[j][4*k+2] = v.z; w[j][4*k+3] = v.w;
        }
    }
    float4 bb = *reinterpret_cast<const float4*>(w2Bb + ob);
    float bias[4] = {bb.x, bb.y, bb.z, bb.w};

    for (int t = 0; t < 16; ++t) {
        float res[4];
        #pragma unroll
        for (int j = 0; j < 4; ++j) {
            float a = bias[j];
            #pragma unroll
            for (int r = 0; r < 16; ++r)
                a = fmaf(s_h2[t][r], w[j][r], a);
            res[j] = a * SCALING;
        }
        *reinterpret_cast<float4*>(out + (size_t)(t0 + t) * 4096 + ob) =
            make_float4(res[0], res[1], res[2], res[3]);
    }
}

extern "C" void kernel_launch(void* const* d_in, const int* in_sizes, int n_in,
                              void* d_out, int out_size, void* d_ws, size_t ws_size,
                              hipStream_t stream) {
    const float* x    = (const float*)d_in[0];
    const float* w1A  = (const float*)d_in[1];
    const float* w1Ab = (const float*)d_in[2];
    const float* w1B  = (const float*)d_in[3];
    const float* w1Bb = (const float*)d_in[4];
    const float* w3A  = (const float*)d_in[5];
    const float* w3Ab = (const float*)d_in[6];
    const float* w3B  = (const float*)d_in[7];
    const float* w3Bb = (const float*)d_in[8];
    const float* w2A  = (const float*)d_in[9];
    const float* w2Ab = (const float*)d_in[10];
    const float* w2B  = (const float*)d_in[11];
    const float* w2Bb = (const float*)d_in[12];
    float* out = (float*)d_out;

    float* ws   = (float*)d_ws;
    float* w2aT = ws;                                   // FFN*16
    float* h13  = w2aT + (size_t)FFN * R;               // 2*TOKENS*32
    float* h2   = h13 + (size_t)K1_SPLIT * TOKENS * 32; // TOKENS*16

    hipMemsetAsync(h2, 0, (size_t)TOKENS * R * sizeof(float), stream);
    k_transpose_w2a<<<(R * FFN + 255) / 256, 256, 0, stream>>>(w2A, w2aT);
    k1_xproj<<<dim3(TOKENS / 8, K1_SPLIT), 256, 0, stream>>>(x, w1A, w3A, h13);
    k2_mid<<<dim3(TOKENS / K2_TOK, FFN / (K2_FPT * K2_WAVES)), 256, 0, stream>>>(
        h13, w1Ab, w3Ab, w1B, w1Bb, w3B, w3Bb, w2aT, h2);
    k3_out<<<dim3(TOKENS / 16, 4096 / 1024), 256, 0, stream>>>(
        h2, w2Ab, w2B, w2Bb, out);
}

// Round 5
// 86.782 us; speedup vs baseline: 7.6167x; 7.6167x over previous
//
#include <hip/hip_runtime.h>

#define TOKENS 4096
#define HIDDEN 4096
#define FFN    14336
#define SCALING 2.0f

typedef short short8 __attribute__((ext_vector_type(8)));
typedef float f32x16 __attribute__((ext_vector_type(16)));

// ---------------------------------------------------------------------------
// ws layout (bytes). All fragments use the 32x32x16 MFMA layouts:
//   A frag: lane l (m=l&31, h=l>>5) holds 8 bf16: row m, k = 8h+i
//   B frag: lane l (n=l&31, h=l>>5) holds 8 bf16: col n, k = 8h+i
//   C/D frag: lane l, reg j: row = (j&3)+8*(j>>2)+4h, col = l&31
// ---------------------------------------------------------------------------
#define OFF_WAPK   ((size_t)0)         // [256 k-tiles][64 lanes][8 bf16]  w1A|w3A N-stacked
#define OFF_W1BPK  ((size_t)262144)    // [448 f-tiles][64][8 bf16]  2*w1B  (A-frag, m=f,k=r)
#define OFF_W3BPK  ((size_t)720896)    // [448][64][8]               2*w3B
#define OFF_W2APK  ((size_t)1179648)   // [896 16f-subtiles][64][8]  w2A    (B-frag, k=f,n=r; n>=16 zero)
#define OFF_B1PK   ((size_t)2097152)   // [448][2 halves][16 f32]    2*w1Bb in C-frag order
#define OFF_B3PK   ((size_t)2154496)   // [448][2][16]               2*w3Bb
#define OFF_H13PK  ((size_t)2211840)   // [128 tok-tiles][64][2][8 bf16]  h-projections B-frag
#define OFF_SLAB   ((size_t)2473984)   // [4 splits][4096][32] f32   k1 partial sums
#define OFF_H2S    ((size_t)4571136)   // [7 chunks][4096][16] f32   k2 partial h2
// end 6406144 (6.4 MB)

__device__ __forceinline__ uint32_t pk_bf16(float a, float b) {
    uint32_t r;
    asm("v_cvt_pk_bf16_f32 %0, %1, %2" : "=v"(r) : "v"(a), "v"(b));
    return r;
}

// ---------------- P0: one-time weight packing to fragment layouts -----------
__global__ __launch_bounds__(256) void p0_pack(
    const float* __restrict__ w1A, const float* __restrict__ w3A,
    const float* __restrict__ w1B, const float* __restrict__ w3B,
    const float* __restrict__ w2A,
    const float* __restrict__ w1Bb, const float* __restrict__ w3Bb,
    char* __restrict__ ws)
{
    const int g = blockIdx.x * 256 + threadIdx.x;

    if (g < 16384) {                       // wApk: [kt][l] <- Wstack[n=c][k=kt*16+8h+i]
        int l = g & 63, kt = g >> 6, c = l & 31, h = l >> 5;
        int k = kt * 16 + 8 * h;
        const float* s = (c < 16) ? (w1A + (size_t)c * HIDDEN + k)
                                  : (w3A + (size_t)(c - 16) * HIDDEN + k);
        float4 a = *(const float4*)s, b = *(const float4*)(s + 4);
        uint4 o = make_uint4(pk_bf16(a.x, a.y), pk_bf16(a.z, a.w),
                             pk_bf16(b.x, b.y), pk_bf16(b.z, b.w));
        ((uint4*)(ws + OFF_WAPK))[g] = o;
    } else if (g < 45056) {                // w1bpk: [ft][l] <- 2*w1B[f=ft*32+c][r=8h+i]
        int t = g - 16384, l = t & 63, ft = t >> 6, c = l & 31, h = l >> 5;
        const float* s = w1B + (size_t)(ft * 32 + c) * 16 + 8 * h;
        float4 a = *(const float4*)s, b = *(const float4*)(s + 4);
        uint4 o = make_uint4(pk_bf16(a.x * 2.f, a.y * 2.f), pk_bf16(a.z * 2.f, a.w * 2.f),
                             pk_bf16(b.x * 2.f, b.y * 2.f), pk_bf16(b.z * 2.f, b.w * 2.f));
        ((uint4*)(ws + OFF_W1BPK))[t] = o;
    } else if (g < 73728) {                // w3bpk
        int t = g - 45056, l = t & 63, ft = t >> 6, c = l & 31, h = l >> 5;
        const float* s = w3B + (size_t)(ft * 32 + c) * 16 + 8 * h;
        float4 a = *(const float4*)s, b = *(const float4*)(s + 4);
        uint4 o = make_uint4(pk_bf16(a.x * 2.f, a.y * 2.f), pk_bf16(a.z * 2.f, a.w * 2.f),
                             pk_bf16(b.x * 2.f, b.y * 2.f), pk_bf16(b.z * 2.f, b.w * 2.f));
        ((uint4*)(ws + OFF_W3BPK))[t] = o;
    } else if (g < 131072) {               // w2apk: [st][l] <- w2A[r=c][f=st*16+8h+i], zero for c>=16
        int t = g - 73728, l = t & 63, st = t >> 6, c = l & 31, h = l >> 5;
        uint4 o = make_uint4(0u, 0u, 0u, 0u);
        if (c < 16) {
            const float* s = w2A + (size_t)c * FFN + st * 16 + 8 * h;
            float4 a = *(const float4*)s, b = *(const float4*)(s + 4);
            o = make_uint4(pk_bf16(a.x, a.y), pk_bf16(a.z, a.w),
                           pk_bf16(b.x, b.y), pk_bf16(b.z, b.w));
        }
        ((uint4*)(ws + OFF_W2APK))[t] = o;
    } else if (g < 145408) {               // b1pk: [ft][h][j] = 2*w1Bb[ft*32+(j&3)+8*(j>>2)+4h]
        int t = g - 131072, ft = t >> 5, rest = t & 31, h = rest >> 4, j = rest & 15;
        int f = ft * 32 + (j & 3) + 8 * (j >> 2) + 4 * h;
        ((float*)(ws + OFF_B1PK))[t] = 2.f * w1Bb[f];
    } else if (g < 159744) {               // b3pk
        int t = g - 145408, ft = t >> 5, rest = t & 31, h = rest >> 4, j = rest & 15;
        int f = ft * 32 + (j & 3) + 8 * (j >> 2) + 4 * h;
        ((float*)(ws + OFF_B3PK))[t] = 2.f * w3Bb[f];
    }
}

// ---------------- K1: x-projection via MFMA -------------------------------
// 4 waves/block share one 32-token tile; K split 4-way across grid.y and
// 4-way across waves (16 k-tiles each). LDS reduce -> f32 slab.
__global__ __launch_bounds__(256, 2) void k1_xproj(
    const float* __restrict__ x, const uint4* __restrict__ wApk,
    float* __restrict__ slab)
{
    __shared__ float s_red[4][32][32];   // 16 KB
    const int tid = threadIdx.x;
    const int w = tid >> 6, l = tid & 63, c = l & 31, h = l >> 5;
    const int t0 = blockIdx.x * 32;
    const int by = blockIdx.y;

    f32x16 acc;
    #pragma unroll
    for (int j = 0; j < 16; ++j) acc[j] = 0.f;

    const float* xr = x + (size_t)(t0 + c) * HIDDEN + 8 * h;
    const int kt0 = by * 64 + w * 16;
    #pragma unroll 4
    for (int kt = kt0; kt < kt0 + 16; ++kt) {
        const float* xp = xr + kt * 16;
        float4 a0 = *(const float4*)xp, a1 = *(const float4*)(xp + 4);
        uint4 ua = make_uint4(pk_bf16(a0.x, a0.y), pk_bf16(a0.z, a0.w),
                              pk_bf16(a1.x, a1.y), pk_bf16(a1.z, a1.w));
        short8 av = __builtin_bit_cast(short8, ua);
        short8 bv = __builtin_bit_cast(short8, wApk[(size_t)kt * 64 + l]);
        acc = __builtin_amdgcn_mfma_f32_32x32x16_bf16(av, bv, acc, 0, 0, 0);
    }
    #pragma unroll
    for (int j = 0; j < 16; ++j) {
        int row = (j & 3) + 8 * (j >> 2) + 4 * h;
        s_red[w][row][c] = acc[j];
    }
    __syncthreads();
    float* sl = slab + (size_t)by * TOKENS * 32;
    for (int p = tid; p < 1024; p += 256) {
        int row = p >> 5, cc = p & 31;
        float s = s_red[0][row][cc] + s_red[1][row][cc]
                + s_red[2][row][cc] + s_red[3][row][cc];
        sl[(size_t)(t0 + row) * 32 + cc] = s;
    }
}

// ---------------- K1b: sum slabs + A-bias, pack h13 to bf16 B-fragments -----
__global__ __launch_bounds__(256) void k1b_combine(
    const float* __restrict__ slab,
    const float* __restrict__ w1Ab, const float* __restrict__ w3Ab,
    uint4* __restrict__ h13pk)
{
    const int g = blockIdx.x * 256 + threadIdx.x;   // 0..8191
    const int l = g & 63, c = l & 31, h = l >> 5;
    const int tt = g >> 6;
    const int token = tt * 32 + c;

    float a[8], b[8];
    {
        float4 a0 = *(const float4*)(w1Ab + 8 * h), a1 = *(const float4*)(w1Ab + 8 * h + 4);
        float4 b0 = *(const float4*)(w3Ab + 8 * h), b1 = *(const float4*)(w3Ab + 8 * h + 4);
        a[0]=a0.x; a[1]=a0.y; a[2]=a0.z; a[3]=a0.w; a[4]=a1.x; a[5]=a1.y; a[6]=a1.z; a[7]=a1.w;
        b[0]=b0.x; b[1]=b0.y; b[2]=b0.z; b[3]=b0.w; b[4]=b1.x; b[5]=b1.y; b[6]=b1.z; b[7]=b1.w;
    }
    #pragma unroll
    for (int s = 0; s < 4; ++s) {
        const float* p = slab + ((size_t)s * TOKENS + token) * 32 + 8 * h;
        float4 v0 = *(const float4*)p,        v1 = *(const float4*)(p + 4);
        float4 u0 = *(const float4*)(p + 16), u1 = *(const float4*)(p + 20);
        a[0]+=v0.x; a[1]+=v0.y; a[2]+=v0.z; a[3]+=v0.w;
        a[4]+=v1.x; a[5]+=v1.y; a[6]+=v1.z; a[7]+=v1.w;
        b[0]+=u0.x; b[1]+=u0.y; b[2]+=u0.z; b[3]+=u0.w;
        b[4]+=u1.x; b[5]+=u1.y; b[6]+=u1.z; b[7]+=u1.w;
    }
    h13pk[(size_t)g * 2]     = make_uint4(pk_bf16(a[0],a[1]), pk_bf16(a[2],a[3]),
                                          pk_bf16(a[4],a[5]), pk_bf16(a[6],a[7]));
    h13pk[(size_t)g * 2 + 1] = make_uint4(pk_bf16(b[0],b[1]), pk_bf16(b[2],b[3]),
                                          pk_bf16(b[4],b[5]), pk_bf16(b[6],b[7]));
}

// ---------------- K2: fused mid  (mfma1 -> silu -> permlane -> mfma2) -------
// v_permlane32_swap_b32 DST, SRC exchanges DST.lanes[32:63] <-> SRC.lanes[0:31]
// (derivation: guide SB T12 recipe -- swap(cvtpk(p0,p1), cvtpk(p4,p5)) must
// leave BOTH outputs as valid A-frag regs; only this convention does).
// Assembly of mfma2 A-frags: swap(q0,q2) -> q0=[h0:f01|h1:f89]=reg0,
// q2=[h0:f45|h1:f1213]=reg2; similarly (q1,q3),(q4,q6),(q5,q7).
__global__ __launch_bounds__(256, 3) void k2_mid(
    const uint4* __restrict__ h13pk,
    const uint4* __restrict__ w1bpk, const uint4* __restrict__ w3bpk,
    const uint4* __restrict__ w2apk,
    const float* __restrict__ b1pk, const float* __restrict__ b3pk,
    float* __restrict__ h2s)
{
    __shared__ float s_acc[4][32][16];
    const int tid = threadIdx.x;
    const int w = tid >> 6, l = tid & 63, c = l & 31, h = l >> 5;
    const int tt = blockIdx.x, t0 = tt * 32, by = blockIdx.y;

    const short8 hA8 = __builtin_bit_cast(short8, h13pk[(size_t)(tt * 64 + l) * 2]);
    const short8 hB8 = __builtin_bit_cast(short8, h13pk[(size_t)(tt * 64 + l) * 2 + 1]);

    f32x16 acc;
    #pragma unroll
    for (int j = 0; j < 16; ++j) acc[j] = 0.f;

    #pragma unroll 2
    for (int it = 0; it < 16; ++it) {
        const int ft = by * 64 + w * 16 + it;
        short8 a1g = __builtin_bit_cast(short8, w1bpk[(size_t)ft * 64 + l]);
        short8 a1u = __builtin_bit_cast(short8, w3bpk[(size_t)ft * 64 + l]);
        short8 b2a = __builtin_bit_cast(short8, w2apk[(size_t)(ft * 2) * 64 + l]);
        short8 b2b = __builtin_bit_cast(short8, w2apk[(size_t)(ft * 2 + 1) * 64 + l]);

        const float* bg = b1pk + ((size_t)ft * 2 + h) * 16;
        const float* bu = b3pk + ((size_t)ft * 2 + h) * 16;
        float4 g0 = *(const float4*)bg,       g1 = *(const float4*)(bg + 4);
        float4 g2 = *(const float4*)(bg + 8), g3 = *(const float4*)(bg + 12);
        float4 u0 = *(const float4*)bu,       u1 = *(const float4*)(bu + 4);
        float4 u2 = *(const float4*)(bu + 8), u3 = *(const float4*)(bu + 12);
        f32x16 Cg, Cu;
        Cg[0]=g0.x; Cg[1]=g0.y; Cg[2]=g0.z; Cg[3]=g0.w;
        Cg[4]=g1.x; Cg[5]=g1.y; Cg[6]=g1.z; Cg[7]=g1.w;
        Cg[8]=g2.x; Cg[9]=g2.y; Cg[10]=g2.z; Cg[11]=g2.w;
        Cg[12]=g3.x; Cg[13]=g3.y; Cg[14]=g3.z; Cg[15]=g3.w;
        Cu[0]=u0.x; Cu[1]=u0.y; Cu[2]=u0.z; Cu[3]=u0.w;
        Cu[4]=u1.x; Cu[5]=u1.y; Cu[6]=u1.z; Cu[7]=u1.w;
        Cu[8]=u2.x; Cu[9]=u2.y; Cu[10]=u2.z; Cu[11]=u2.w;
        Cu[12]=u3.x; Cu[13]=u3.y; Cu[14]=u3.z; Cu[15]=u3.w;

        // D1[f][token] with bias as C-init; weights pre-scaled by 2
        f32x16 d1g = __builtin_amdgcn_mfma_f32_32x32x16_bf16(a1g, hA8, Cg, 0, 0, 0);
        f32x16 d1u = __builtin_amdgcn_mfma_f32_32x32x16_bf16(a1u, hB8, Cu, 0, 0, 0);

        float hv[16];
        #pragma unroll
        for (int j = 0; j < 16; ++j) {
            float gg = d1g[j];
            float sig = __builtin_amdgcn_rcpf(1.f + __expf(-gg));
            hv[j] = gg * sig * d1u[j];
        }
        uint32_t q0 = pk_bf16(hv[0], hv[1]),   q1 = pk_bf16(hv[2], hv[3]);
        uint32_t q2 = pk_bf16(hv[4], hv[5]),   q3 = pk_bf16(hv[6], hv[7]);
        uint32_t q4 = pk_bf16(hv[8], hv[9]),   q5 = pk_bf16(hv[10], hv[11]);
        uint32_t q6 = pk_bf16(hv[12], hv[13]), q7 = pk_bf16(hv[14], hv[15]);
        // DST.high <-> SRC.low ; DST = LOWER q index (see header comment)
        asm("v_permlane32_swap_b32 %0, %1" : "+v"(q0), "+v"(q2));
        asm("v_permlane32_swap_b32 %0, %1" : "+v"(q1), "+v"(q3));
        asm("v_permlane32_swap_b32 %0, %1" : "+v"(q4), "+v"(q6));
        asm("v_permlane32_swap_b32 %0, %1" : "+v"(q5), "+v"(q7));
        short8 a2a = __builtin_bit_cast(short8, make_uint4(q0, q1, q2, q3));
        short8 a2b = __builtin_bit_cast(short8, make_uint4(q4, q5, q6, q7));

        acc = __builtin_amdgcn_mfma_f32_32x32x16_bf16(a2a, b2a, acc, 0, 0, 0);
        acc = __builtin_amdgcn_mfma_f32_32x32x16_bf16(a2b, b2b, acc, 0, 0, 0);
    }

    if (c < 16) {
        #pragma unroll
        for (int j = 0; j < 16; ++j)
            s_acc[w][(j & 3) + 8 * (j >> 2) + 4 * h][c] = acc[j];
    }
    __syncthreads();
    for (int p = tid; p < 512; p += 256) {
        int tok = p >> 4, r = p & 15;
        float s = s_acc[0][tok][r] + s_acc[1][tok][r] + s_acc[2][tok][r] + s_acc[3][tok][r];
        h2s[((size_t)by * TOKENS + t0 + tok) * 16 + r] = s;
    }
}

// ---------------- K3: out = ((sum_chunks h2 + w2Ab) @ w2B.T + w2Bb) * 2 -----
__global__ __launch_bounds__(256) void k3_out(
    const float* __restrict__ h2s,
    const float* __restrict__ w2Ab,
    const float* __restrict__ w2B, const float* __restrict__ w2Bb,
    float* __restrict__ out)
{
    __shared__ float s_h2[16][16];
    const int tid = threadIdx.x;
    const int t0 = blockIdx.x * 16;
    const int o0 = blockIdx.y * 1024;

    {
        int t = tid >> 4, r = tid & 15;
        float a = w2Ab[r];
        #pragma unroll
        for (int s = 0; s < 7; ++s)
            a += h2s[((size_t)s * TOKENS + t0 + t) * 16 + r];
        s_h2[t][r] = a;
    }
    __syncthreads();

    const int ob = o0 + tid * 4;
    float w[4][16];
    #pragma unroll
    for (int j = 0; j < 4; ++j) {
        #pragma unroll
        for (int k = 0; k < 4; ++k) {
            float4 v = *(const float4*)(w2B + (size_t)(ob + j) * 16 + k * 4);
            w[j][4*k+0] = v.x; w[j][4*k+1] = v.y;
            w[j][4*k+2] = v.z; w[j][4*k+3] = v.w;
        }
    }
    float4 bb = *(const float4*)(w2Bb + ob);
    float bias[4] = {bb.x, bb.y, bb.z, bb.w};

    for (int t = 0; t < 16; ++t) {
        float res[4];
        #pragma unroll
        for (int j = 0; j < 4; ++j) {
            float a = bias[j];
            #pragma unroll
            for (int r = 0; r < 16; ++r)
                a = fmaf(s_h2[t][r], w[j][r], a);
            res[j] = a * SCALING;
        }
        *(float4*)(out + (size_t)(t0 + t) * 4096 + ob) =
            make_float4(res[0], res[1], res[2], res[3]);
    }
}

extern "C" void kernel_launch(void* const* d_in, const int* in_sizes, int n_in,
                              void* d_out, int out_size, void* d_ws, size_t ws_size,
                              hipStream_t stream) {
    const float* x    = (const float*)d_in[0];
    const float* w1A  = (const float*)d_in[1];
    const float* w1Ab = (const float*)d_in[2];
    const float* w1B  = (const float*)d_in[3];
    const float* w1Bb = (const float*)d_in[4];
    const float* w3A  = (const float*)d_in[5];
    const float* w3Ab = (const float*)d_in[6];
    const float* w3B  = (const float*)d_in[7];
    const float* w3Bb = (const float*)d_in[8];
    const float* w2A  = (const float*)d_in[9];
    const float* w2Ab = (const float*)d_in[10];
    const float* w2B  = (const float*)d_in[11];
    const float* w2Bb = (const float*)d_in[12];
    float* out = (float*)d_out;

    char* ws = (char*)d_ws;
    const uint4* wApk  = (const uint4*)(ws + OFF_WAPK);
    const uint4* w1bpk = (const uint4*)(ws + OFF_W1BPK);
    const uint4* w3bpk = (const uint4*)(ws + OFF_W3BPK);
    const uint4* w2apk = (const uint4*)(ws + OFF_W2APK);
    const float* b1pk  = (const float*)(ws + OFF_B1PK);
    const float* b3pk  = (const float*)(ws + OFF_B3PK);
    uint4* h13pk = (uint4*)(ws + OFF_H13PK);
    float* slab  = (float*)(ws + OFF_SLAB);
    float* h2s   = (float*)(ws + OFF_H2S);

    p0_pack<<<624, 256, 0, stream>>>(w1A, w3A, w1B, w3B, w2A, w1Bb, w3Bb, ws);
    k1_xproj<<<dim3(128, 4), 256, 0, stream>>>(x, wApk, slab);
    k1b_combine<<<32, 256, 0, stream>>>(slab, w1Ab, w3Ab, h13pk);
    k2_mid<<<dim3(128, 7), 256, 0, stream>>>(h13pk, w1bpk, w3bpk, w2apk, b1pk, b3pk, h2s);
    k3_out<<<dim3(256, 4), 256, 0, stream>>>(h2s, w2Ab, w2B, w2Bb, out);
}